// Round 20
// baseline (114.976 us; speedup 1.0000x reference)
//
#include <hip/hip_runtime.h>
#include <hip/hip_bf16.h>
#include <cstdint>
#include <cstddef>

typedef unsigned int u32;
typedef __attribute__((ext_vector_type(8))) short s16x8;   // 8 bf16 (4 VGPR) MFMA A/B frag
typedef __attribute__((ext_vector_type(4))) short s16x4;   // 4 bf16, 8B pack
typedef __attribute__((ext_vector_type(4))) float f32x4;   // MFMA C/D frag
typedef __attribute__((ext_vector_type(2))) u32   u32x2;

#define MFMA(a,b,c) __builtin_amdgcn_mfma_f32_16x16x32_bf16(a,b,c,0,0,0)

#if __has_builtin(__builtin_amdgcn_mfma_f32_16x16x16bf16_1k)
#define MFMA16(a,b,c) __builtin_amdgcn_mfma_f32_16x16x16bf16_1k(a,b,c,0,0,0)
#else
static __device__ __forceinline__ f32x4 MFMA16(s16x4 a, s16x4 b, f32x4 c){
    f32x4 d;
    asm("v_mfma_f32_16x16x16_bf16 %0, %1, %2, %3"
        : "=v"(d) : "v"(a), "v"(b), "v"(c));
    return d;
}
#endif

#define LOG2E 1.4426950408889634f

// device fast 2^x (v_exp_f32 computes 2^x natively)
__device__ __forceinline__ float fexp2(float x) {
    return __builtin_amdgcn_exp2f(x);
}

__device__ __forceinline__ short f2bf(float f) {
    u32 u = __builtin_bit_cast(u32, f);
    u32 r = (u + 0x7fffu + ((u >> 16) & 1u)) >> 16;   // RNE
    return (short)r;
}
__device__ __forceinline__ float bf2f(short s) {
    return __builtin_bit_cast(float, ((u32)(unsigned short)s) << 16);
}
__device__ __forceinline__ u32 cvtpk(float lo, float hi) {
    u32 r;
    asm("v_cvt_pk_bf16_f32 %0, %1, %2" : "=v"(r) : "v"(lo), "v"(hi));
    return r;
}
__device__ __forceinline__ void async_copy16(void* lds, const void* g) {
    __builtin_amdgcn_global_load_lds((const __attribute__((address_space(1))) u32*)g,
                                     (__attribute__((address_space(3))) u32*)lds, 16, 0, 0);
}

// ---------------------------------------------------------------------------
// prep_all: fused {cast_x | transpose_w | tables + maskP(log2-domain)}
// ---------------------------------------------------------------------------
__global__ __launch_bounds__(256)
void prep_all(const float* __restrict__ x, short* __restrict__ xb,
              const float* __restrict__ wq, const float* __restrict__ wk,
              const float* __restrict__ wv, const float* __restrict__ wo,
              short* __restrict__ Wtqkv, short* __restrict__ Wto,
              const float* __restrict__ relk, const float* __restrict__ relv,
              short* __restrict__ relkb, short* __restrict__ relvT,
              const float* __restrict__ mask, short* __restrict__ maskPb)
{
    __shared__ float sT[64][68];
    const int bid = blockIdx.x;
    const int tid = threadIdx.x;

    if (bid < 2048) {
        int i = (bid * 256 + tid) * 8;
        float4 a = *(const float4*)&x[i];
        float4 b = *(const float4*)&x[i + 4];
        s16x8 v = { f2bf(a.x), f2bf(a.y), f2bf(a.z), f2bf(a.w),
                    f2bf(b.x), f2bf(b.y), f2bf(b.z), f2bf(b.w) };
        *(s16x8*)&xb[i] = v;
    } else if (bid < 3072) {
        const int wid = bid - 2048;
        const int kt = wid & 15, nt = (wid >> 4) & 15, seg = wid >> 8;
        const float* src = seg == 0 ? wq : seg == 1 ? wk : seg == 2 ? wv : wo;
        const int k0 = kt * 64, n0 = nt * 64;
#pragma unroll
        for (int i = 0; i < 4; ++i) {
            int t2 = tid + i * 256;
            int r = t2 >> 4, c4 = t2 & 15;
            *(float4*)&sT[r][c4 * 4] = *(const float4*)&src[(size_t)(k0 + r) * 1024 + n0 + c4 * 4];
        }
        __syncthreads();
#pragma unroll
        for (int i = 0; i < 2; ++i) {
            int t2 = tid + i * 256;
            int rn = t2 >> 3, ch = t2 & 7;
            s16x8 v;
#pragma unroll
            for (int j = 0; j < 8; ++j) v[j] = f2bf(sT[ch * 8 + j][rn]);
            if (seg < 3)
                *(s16x8*)&Wtqkv[(size_t)(seg * 1024 + n0 + rn) * 1024 + k0 + ch * 8] = v;
            else
                *(s16x8*)&Wto[(size_t)(n0 + rn) * 1024 + k0 + ch * 8] = v;
        }
    } else {
        int gt = (bid - 3072) * 256 + tid;
        for (int i = gt; i < 144 * 64; i += 256 * 8) {
            int r = i >> 6, d = i & 63;
            relkb[i] = (r < 129) ? f2bf(relk[r * 64 + d]) : (short)0;
        }
        for (int i = gt; i < 64 * 128; i += 256 * 8) {
            int d = i >> 7, r = i & 127;
            relvT[i] = f2bf(relv[r * 64 + d]);
        }
        for (int i = gt; i < 4096; i += 256 * 8)
            maskPb[i] = f2bf(mask[i] * (-1e9f * LOG2E));
    }
}

// ---------------------------------------------------------------------------
// Fused QKV GEMM; Q segment scaled by log2(e) (exp2 softmax domain).
// ---------------------------------------------------------------------------
__global__ __launch_bounds__(256, 4)
void gemm_qkv(const short* __restrict__ Ab, const short* __restrict__ Wt,
              const float* __restrict__ bq, const float* __restrict__ bk,
              const float* __restrict__ bv,
              short* __restrict__ Qb, short* __restrict__ Kb, short* __restrict__ Vtb)
{
    __shared__ __align__(16) short As[128 * 64];
    __shared__ __align__(16) short Bs[128 * 64];
    const int tid = threadIdx.x;
    const int w = tid >> 6, lane = tid & 63;
    const int lo16 = lane & 15, hi = lane >> 4;
    const int pb = blockIdx.x;
    const int wg = (pb & 7) * 96 + (pb >> 3);
    const int n0g = (wg % 24) * 128;
    const int m0 = (wg / 24) * 128;
    const int wr = w >> 1, wc = w & 1;

    f32x4 acc[4][4] = {};

    for (int t = 0; t < 16; ++t) {
        const int k0 = t * 64;
        __syncthreads();
#pragma unroll
        for (int i = 0; i < 4; ++i) {
            int o = i * 4096 + tid * 16;
            int row = o >> 7;
            int cb = o & 127;
            int sc = cb ^ ((row & 7) << 4);
            async_copy16((char*)As + o, Ab + (size_t)(m0 + row) * 1024 + k0 + (sc >> 1));
            async_copy16((char*)Bs + o, Wt + (size_t)(n0g + row) * 1024 + k0 + (sc >> 1));
        }
        __syncthreads();
#pragma unroll
        for (int ks = 0; ks < 2; ++ks) {
            s16x8 aF[4], bF[4];
#pragma unroll
            for (int mi = 0; mi < 4; ++mi) {
                int row = wr * 64 + mi * 16 + lo16;
                int cb = ks * 64 + hi * 16;
                aF[mi] = *(const s16x8*)((const char*)As + row * 128 + (cb ^ ((row & 7) << 4)));
            }
#pragma unroll
            for (int ni = 0; ni < 4; ++ni) {
                int row = wc * 64 + ni * 16 + lo16;
                int cb = ks * 64 + hi * 16;
                bF[ni] = *(const s16x8*)((const char*)Bs + row * 128 + (cb ^ ((row & 7) << 4)));
            }
#pragma unroll
            for (int mi = 0; mi < 4; ++mi)
#pragma unroll
                for (int ni = 0; ni < 4; ++ni)
                    acc[mi][ni] = MFMA(aF[mi], bF[ni], acc[mi][ni]);
        }
    }

    const int seg = n0g >> 10;
    const int nn = n0g & 1023;
    const float* bias = seg == 0 ? bq : seg == 1 ? bk : bv;
    const float oscale = (seg == 0) ? LOG2E : 1.0f;   // Q in log2-exp domain
    float bv4[4];
#pragma unroll
    for (int ni = 0; ni < 4; ++ni) bv4[ni] = bias[nn + wc * 64 + ni * 16 + lo16];

    if (seg == 2) {
#pragma unroll
        for (int mi = 0; mi < 4; ++mi)
#pragma unroll
            for (int ni = 0; ni < 4; ++ni) {
                int nl = nn + wc * 64 + ni * 16 + lo16;
                int hh = nl >> 6, d = nl & 63;
                int mbase = m0 + wr * 64 + mi * 16 + hi * 4;
                int bb = mbase >> 10, l0 = mbase & 1023;
                int j0 = l0 & 31;
                int col = (l0 >> 5) * 32 + (((j0 >> 4) & 1) << 2) + (((j0 >> 2) & 3) << 3);
                s16x4 pk = { f2bf(acc[mi][ni][0] + bv4[ni]),
                             f2bf(acc[mi][ni][1] + bv4[ni]),
                             f2bf(acc[mi][ni][2] + bv4[ni]),
                             f2bf(acc[mi][ni][3] + bv4[ni]) };
                *(s16x4*)&Vtb[((size_t)(bb * 16 + hh) * 64 + d) * 1024 + col] = pk;
            }
    } else {
        short* out = seg == 0 ? Qb : Kb;
#pragma unroll
        for (int mi = 0; mi < 4; ++mi)
#pragma unroll
            for (int ni = 0; ni < 4; ++ni) {
                int nl = nn + wc * 64 + ni * 16 + lo16;
                int hh = nl >> 6, d = nl & 63;
#pragma unroll
                for (int r = 0; r < 4; ++r) {
                    int m = m0 + wr * 64 + mi * 16 + hi * 4 + r;
                    int bb = m >> 10, l = m & 1023;
                    out[(((size_t)bb * 16 + hh) * 1024 + l) * 64 + d] =
                        f2bf((acc[mi][ni][r] + bv4[ni]) * oscale);
                }
            }
    }
}

// ---------------------------------------------------------------------------
// Flash attention v13b: K/V double-buffered 32-k chunks -> ONE __syncthreads
// per chunk. sQrel/sBand MERGED in-place (gather-then-scatter per slot).
// LDS = 32768B -> 4 blocks/CU. exp2 softmax (log2 domain).
// ---------------------------------------------------------------------------
__global__ __launch_bounds__(256, 4)
void attn_mfma(const short* __restrict__ Qb, const short* __restrict__ Kb,
               const short* __restrict__ Vtb, const short* __restrict__ relkb,
               const short* __restrict__ relvTb, const float* __restrict__ relv_f32,
               const short* __restrict__ maskPb, short* __restrict__ CTXb)
{
    __shared__ __align__(16) short sK[2][32 * 64];     // 8192B, swizzled chunks
    __shared__ __align__(16) short sV[2][64 * 32];     // 8192B, interleaved + chunk-swizzled
    __shared__ __align__(16) short sQB[4][16][128];    // 16384B, Qrel -> band (in place), idx ^ qsw

    const int tid = threadIdx.x;
    const int w = tid >> 6, lane = tid & 63;
    const int lo16 = lane & 15, hi = lane >> 4;
    const int qsw = (lo16 & 7) << 4;         // bank swizzle
    const int vm = (lo16 >> 1) & 3;          // V chunk swizzle

    const int p = blockIdx.x;
    const int bid = (p & 7) * 128 + (p >> 3);
    const int bh = bid >> 4;
    const int qt = bid & 15;
    const int b = bh >> 4, h = bh & 15;
    const int q0 = qt * 64 + w * 16;
    const int q_abs = q0 + lo16;

    const short* Kbase = Kb + (size_t)bh * 65536;
    const short* Vtbase = Vtb + (size_t)bh * 65536;
    const short* mbase = maskPb + b * 1024;

    const int skr = tid >> 3, skc = tid & 7;             // K: row 0..31, chunk 0..7
    const int svd = tid >> 2, svc = tid & 3;             // V: row d 0..63, chunk 0..3
    const short* ksrc = Kbase + (size_t)skr * 64 + ((skc ^ (skr & 7)) << 3);
    const short* vsrc = Vtbase + (size_t)svd * 1024 + ((svc ^ ((svd >> 1) & 3)) << 3);

    // stage chunk 0 into buffer 0
    async_copy16((char*)&sK[0][0] + tid * 16, ksrc);
    async_copy16((char*)&sV[0][0] + tid * 16, vsrc);

    const short* qptr = Qb + ((size_t)bh * 1024 + q_abs) * 64 + hi * 8;
    const s16x8 qB0 = *(const s16x8*)qptr;
    const s16x8 qB1 = *(const s16x8*)(qptr + 32);

    // Qrel init: rf 0..7 -> sQB[w][q][(0..127)^qsw]; rf=8 kept in regs
    f32x4 dq8 = {0.f, 0.f, 0.f, 0.f};
#pragma unroll
    for (int rf = 0; rf < 9; ++rf) {
        const short* rp = relkb + (size_t)(rf * 16 + lo16) * 64 + hi * 8;
        s16x8 rA0 = *(const s16x8*)rp;
        s16x8 rA1 = *(const s16x8*)(rp + 32);
        f32x4 dq = {0.f, 0.f, 0.f, 0.f};
        dq = MFMA(rA0, qB0, dq);
        dq = MFMA(rA1, qB1, dq);
        if (rf < 8) {
            s16x4 pk = { f2bf(dq[0]), f2bf(dq[1]), f2bf(dq[2]), f2bf(dq[3]) };
            *(s16x4*)&sQB[w][lo16][(rf * 16 + hi * 4) ^ qsw] = pk;
        } else {
            dq8 = dq;
        }
    }
    // Qrel[q][0] from LDS (slot stays valid through the loop); Qrel[q][128]
    // via wave shuffle from lane q (hi==0 holds it in dq8[0]).
    const float qrel_lo = bf2f(sQB[w][lo16][0 ^ qsw]);
    const float qrel_hi = __shfl(bf2f(f2bf(dq8[0])), lo16);

    __syncthreads();   // drains chunk-0 staging; fences sQB init

    f32x4 ctx[4] = {};
    float lsum = 0.f, lov = 0.f, hiv = 0.f;
    const f32x4 z = {0.f, 0.f, 0.f, 0.f};
    const int km = lo16 & 7;

    for (int t = 0; t < 32; ++t) {
        const int kf = t * 32;
        const int cur = t & 1, nxt = (t + 1) & 1;
        // ---- stage chunk t+1 into the OTHER buffer (no read conflict) ----
        const int kfn = ((t + 1) & 31) * 32;
        async_copy16((char*)&sK[nxt][0] + tid * 16, ksrc + (size_t)kfn * 64);
        async_copy16((char*)&sV[nxt][0] + tid * 16, vsrc + kfn);
        // ---- chunk t LDS -> regs; mask from global (L1) ----
        s16x8 kr0 = *(const s16x8*)(sK[cur] + lo16 * 64 + ((hi ^ km) << 3));
        s16x8 kr1 = *(const s16x8*)(sK[cur] + lo16 * 64 + (((hi + 4) ^ km) << 3));
        s16x8 kr2 = *(const s16x8*)(sK[cur] + (lo16 + 16) * 64 + ((hi ^ km) << 3));
        s16x8 kr3 = *(const s16x8*)(sK[cur] + (lo16 + 16) * 64 + (((hi + 4) ^ km) << 3));
        s16x8 vr0 = *(const s16x8*)(sV[cur] + lo16 * 32 + ((hi ^ vm) << 3));
        s16x8 vr1 = *(const s16x8*)(sV[cur] + (16 + lo16) * 32 + ((hi ^ vm) << 3));
        s16x8 vr2 = *(const s16x8*)(sV[cur] + (32 + lo16) * 32 + ((hi ^ vm) << 3));
        s16x8 vr3 = *(const s16x8*)(sV[cur] + (48 + lo16) * 32 + ((hi ^ vm) << 3));
        s16x4 m0 = *(const s16x4*)&mbase[kf + hi * 4];
        s16x4 m1 = *(const s16x4*)&mbase[kf + 16 + hi * 4];

        // ---- QK (4 MFMAs, 2 chains) ----
        __builtin_amdgcn_s_setprio(1);
        f32x4 s0 = MFMA(kr0, qB0, z);
        f32x4 s1 = MFMA(kr2, qB0, z);
        s0 = MFMA(kr1, qB1, s0);
        s1 = MFMA(kr3, qB1, s1);
        __builtin_amdgcn_s_setprio(0);

        // ---- softmax (log2 domain) ----
        float pr[8];
        if (kf + 95 <= q0 || kf >= q0 + 79) {
            const float qc = (kf < q0) ? qrel_lo : qrel_hi;
            float bs = 0.f;
#pragma unroll
            for (int r = 0; r < 4; ++r) {
                pr[r]     = fexp2(s0[r] + qc + bf2f(m0[r]));
                pr[4 + r] = fexp2(s1[r] + qc + bf2f(m1[r]));
            }
#pragma unroll
            for (int r = 0; r < 8; ++r) bs += pr[r];
            lsum += bs;
            if (kf < q0) lov += bs; else hiv += bs;
        } else {
#pragma unroll
            for (int f = 0; f < 2; ++f)
#pragma unroll
                for (int r = 0; r < 4; ++r) {
                    int k_abs = kf + f * 16 + hi * 4 + r;
                    int dd = k_abs - q_abs;
                    dd = dd < -64 ? -64 : (dd > 64 ? 64 : dd);
                    int rel = dd + 64;
                    int relc = rel > 127 ? 127 : rel;
                    float qv = bf2f(sQB[w][lo16][relc ^ qsw]);   // gather Qrel
                    if (rel == 128) qv = qrel_hi;
                    float sv = f ? s1[r] : s0[r];
                    float mv = bf2f(f ? m1[r] : m0[r]);
                    float pex = fexp2(sv + qv + mv);
                    pr[f * 4 + r] = pex;
                    lsum += pex;
                    if (rel >= 1 && rel <= 127) sQB[w][lo16][rel ^ qsw] = f2bf(pex);  // scatter band (same slot)
                    else if (rel == 0) lov += pex;
                    else hiv += pex;
                }
        }
        u32x2 w0 = { cvtpk(pr[0], pr[1]), cvtpk(pr[2], pr[3]) };
        u32x2 w1 = { cvtpk(pr[4], pr[5]), cvtpk(pr[6], pr[7]) };
        s16x4 pf0 = __builtin_bit_cast(s16x4, w0);
        s16x4 pf1 = __builtin_bit_cast(s16x4, w1);

        // ---- PV (8 MFMAs) ----
        s16x4 a0 = __builtin_shufflevector(vr0, vr0, 0, 1, 2, 3);
        s16x4 b0 = __builtin_shufflevector(vr0, vr0, 4, 5, 6, 7);
        s16x4 a1 = __builtin_shufflevector(vr1, vr1, 0, 1, 2, 3);
        s16x4 b1 = __builtin_shufflevector(vr1, vr1, 4, 5, 6, 7);
        s16x4 a2 = __builtin_shufflevector(vr2, vr2, 0, 1, 2, 3);
        s16x4 b2 = __builtin_shufflevector(vr2, vr2, 4, 5, 6, 7);
        s16x4 a3 = __builtin_shufflevector(vr3, vr3, 0, 1, 2, 3);
        s16x4 b3 = __builtin_shufflevector(vr3, vr3, 4, 5, 6, 7);
        __builtin_amdgcn_s_setprio(1);
        ctx[0] = MFMA16(a0, pf0, ctx[0]);
        ctx[1] = MFMA16(a1, pf0, ctx[1]);
        ctx[2] = MFMA16(a2, pf0, ctx[2]);
        ctx[3] = MFMA16(a3, pf0, ctx[3]);
        ctx[0] = MFMA16(b0, pf1, ctx[0]);
        ctx[1] = MFMA16(b1, pf1, ctx[1]);
        ctx[2] = MFMA16(b2, pf1, ctx[2]);
        ctx[3] = MFMA16(b3, pf1, ctx[3]);
        __builtin_amdgcn_s_setprio(0);

        __syncthreads();   // drains this iter's staging + all waves' reads of buf[cur]
    }

    // ---- finalize band array: zero slot 0 (held Qrel[0]) and unvisited
    //      edge slots (qt 0/15: k out of [0,1024)) ----
    if (hi == 0) {
        sQB[w][lo16][0 ^ qsw] = 0;
        if (qt == 0) {
            for (int rel = 1; rel <= 63 - q_abs; ++rel)
                sQB[w][lo16][rel ^ qsw] = 0;
        } else if (qt == 15) {
            for (int rel = 1088 - q_abs; rel <= 127; ++rel)
                sQB[w][lo16][rel ^ qsw] = 0;
        }
    }
    __syncthreads();   // robust cross-lane visibility for the contraction

    // band rel_v contribution: ctx^T += relvT-frag x band-frag (unnormalized)
#pragma unroll
    for (int ks = 0; ks < 4; ++ks) {
        s16x8 bB = *(const s16x8*)&sQB[w][lo16][(ks * 32 + hi * 8) ^ qsw];
#pragma unroll
        for (int df = 0; df < 4; ++df) {
            s16x8 rA = *(const s16x8*)(relvTb + (size_t)(df * 16 + lo16) * 128 + ks * 32 + hi * 8);
            ctx[df] = MFMA(rA, bB, ctx[df]);
        }
    }

    // reduce per-q stats across the 4 hi-groups
    lsum += __shfl_xor(lsum, 16); lsum += __shfl_xor(lsum, 32);
    lov  += __shfl_xor(lov, 16);  lov  += __shfl_xor(lov, 32);
    hiv  += __shfl_xor(hiv, 16);  hiv  += __shfl_xor(hiv, 32);
    const float inv = 1.0f / lsum;

    // tails (clipped buckets 0 / 128) + normalize + store bf16 ctx
#pragma unroll
    for (int df = 0; df < 4; ++df) {
        s16x4 pk;
#pragma unroll
        for (int r = 0; r < 4; ++r) {
            int d = df * 16 + hi * 4 + r;
            float t = ctx[df][r] + lov * relv_f32[d] + hiv * relv_f32[128 * 64 + d];
            pk[r] = f2bf(t * inv);
        }
        *(s16x4*)(CTXb + ((size_t)(b * 1024) + q_abs) * 1024 + h * 64 + df * 16 + hi * 4) = pk;
    }
}

// ---------------------------------------------------------------------------
// Output GEMM (unchanged): 128x64 tile, 512 blocks, XCD-swizzled.
// ---------------------------------------------------------------------------
__global__ __launch_bounds__(256, 4)
void gemm_out(const short* __restrict__ Ab, const short* __restrict__ Wto,
              const float* __restrict__ bo, float* __restrict__ out)
{
    __shared__ __align__(16) short As[128 * 64];
    __shared__ __align__(16) short Bs[64 * 64];
    const int tid = threadIdx.x;
    const int w = tid >> 6, lane = tid & 63;
    const int lo16 = lane & 15, hi = lane >> 4;
    const int pb = blockIdx.x;
    const int wg = (pb & 7) * 64 + (pb >> 3);
    const int n0 = (wg & 15) * 64;
    const int m0 = (wg >> 4) * 128;
    const int wr = w;

    f32x4 acc[2][4] = {};

    for (int t = 0; t < 16; ++t) {
        const int k0 = t * 64;
        __syncthreads();
#pragma unroll
        for (int i = 0; i < 4; ++i) {
            int o = i * 4096 + tid * 16;
            int row = o >> 7;
            int cb = o & 127;
            int sc = cb ^ ((row & 7) << 4);
            async_copy16((char*)As + o, Ab + (size_t)(m0 + row) * 1024 + k0 + (sc >> 1));
        }
#pragma unroll
        for (int i = 0; i < 2; ++i) {
            int o = i * 4096 + tid * 16;
            int row = o >> 7;
            int cb = o & 127;
            int sc = cb ^ ((row & 7) << 4);
            async_copy16((char*)Bs + o, Wto + (size_t)(n0 + row) * 1024 + k0 + (sc >> 1));
        }
        __syncthreads();
#pragma unroll
        for (int ks = 0; ks < 2; ++ks) {
            s16x8 aF[2], bF[4];
#pragma unroll
            for (int mi = 0; mi < 2; ++mi) {
                int row = wr * 32 + mi * 16 + lo16;
                int cb = ks * 64 + hi * 16;
                aF[mi] = *(const s16x8*)((const char*)As + row * 128 + (cb ^ ((row & 7) << 4)));
            }
#pragma unroll
            for (int ni = 0; ni < 4; ++ni) {
                int row = ni * 16 + lo16;
                int cb = ks * 64 + hi * 16;
                bF[ni] = *(const s16x8*)((const char*)Bs + row * 128 + (cb ^ ((row & 7) << 4)));
            }
#pragma unroll
            for (int mi = 0; mi < 2; ++mi)
#pragma unroll
                for (int ni = 0; ni < 4; ++ni)
                    acc[mi][ni] = MFMA(aF[mi], bF[ni], acc[mi][ni]);
        }
    }

    float bv4[4];
#pragma unroll
    for (int ni = 0; ni < 4; ++ni) bv4[ni] = bo[n0 + ni * 16 + lo16];
#pragma unroll
    for (int mi = 0; mi < 2; ++mi)
#pragma unroll
        for (int ni = 0; ni < 4; ++ni)
#pragma unroll
            for (int r = 0; r < 4; ++r) {
                int m = m0 + wr * 32 + mi * 16 + hi * 4 + r;
                out[(size_t)m * 1024 + n0 + ni * 16 + lo16] = acc[mi][ni][r] + bv4[ni];
            }
}

// ---------------------------------------------------------------------------
extern "C" void kernel_launch(void* const* d_in, const int* in_sizes, int n_in,
                              void* d_out, int out_size, void* d_ws, size_t ws_size,
                              hipStream_t stream)
{
    (void)in_sizes; (void)n_in; (void)out_size; (void)ws_size;
    const float* x    = (const float*)d_in[0];
    const float* mask = (const float*)d_in[1];
    const float* wq   = (const float*)d_in[2];
    const float* bq   = (const float*)d_in[3];
    const float* wk   = (const float*)d_in[4];
    const float* bk   = (const float*)d_in[5];
    const float* wv   = (const float*)d_in[6];
    const float* bv   = (const float*)d_in[7];
    const float* wo   = (const float*)d_in[8];
    const float* bo   = (const float*)d_in[9];
    const float* relk = (const float*)d_in[10];
    const float* relv = (const float*)d_in[11];
    float* out = (float*)d_out;

    char* p = (char*)d_ws;
    short* xb     = (short*)p; p += (size_t)4096 * 1024 * 2;     // 8 MB
    short* Wtqkv  = (short*)p; p += (size_t)3072 * 1024 * 2;     // 6 MB
    short* Wto    = (short*)p; p += (size_t)1024 * 1024 * 2;     // 2 MB
    short* Qb     = (short*)p; p += (size_t)4096 * 1024 * 2;     // 8 MB
    short* Kb     = (short*)p; p += (size_t)4096 * 1024 * 2;     // 8 MB
    short* Vtb    = (short*)p; p += (size_t)4096 * 1024 * 2;     // 8 MB
    short* CTXb   = (short*)p; p += (size_t)4096 * 1024 * 2;     // 8 MB
    short* relkb  = (short*)p; p += (size_t)144 * 64 * 2;
    short* relvT  = (short*)p; p += (size_t)64 * 128 * 2;
    short* maskPb = (short*)p; p += (size_t)4096 * 2;

    prep_all  <<<3080, 256, 0, stream>>>(x, xb, wq, wk, wv, wo, Wtqkv, Wto,
                                         relk, relv, relkb, relvT, mask, maskPb);
    gemm_qkv  <<<768, 256, 0, stream>>>(xb, Wtqkv, bq, bk, bv, Qb, Kb, Vtb);
    attn_mfma <<<1024, 256, 0, stream>>>(Qb, Kb, Vtb, relkb, relvT, relv, maskPb, CTXb);
    gemm_out  <<<512, 256, 0, stream>>>(CTXb, Wto, bo, out);
}

// Round 21
// 113.425 us; speedup vs baseline: 1.0137x; 1.0137x over previous
//
#include <hip/hip_runtime.h>
#include <hip/hip_bf16.h>
#include <cstdint>
#include <cstddef>

typedef unsigned int u32;
typedef __attribute__((ext_vector_type(8))) short s16x8;   // 8 bf16 (4 VGPR) MFMA A/B frag
typedef __attribute__((ext_vector_type(4))) short s16x4;   // 4 bf16, 8B pack
typedef __attribute__((ext_vector_type(4))) float f32x4;   // MFMA C/D frag
typedef __attribute__((ext_vector_type(2))) u32   u32x2;

#define MFMA(a,b,c) __builtin_amdgcn_mfma_f32_16x16x32_bf16(a,b,c,0,0,0)

#if __has_builtin(__builtin_amdgcn_mfma_f32_16x16x16bf16_1k)
#define MFMA16(a,b,c) __builtin_amdgcn_mfma_f32_16x16x16bf16_1k(a,b,c,0,0,0)
#else
static __device__ __forceinline__ f32x4 MFMA16(s16x4 a, s16x4 b, f32x4 c){
    f32x4 d;
    asm("v_mfma_f32_16x16x16_bf16 %0, %1, %2, %3"
        : "=v"(d) : "v"(a), "v"(b), "v"(c));
    return d;
}
#endif

#define LOG2E 1.4426950408889634f

__device__ __forceinline__ float fexp2(float x) {
    return __builtin_amdgcn_exp2f(x);
}

__device__ __forceinline__ short f2bf(float f) {
    u32 u = __builtin_bit_cast(u32, f);
    u32 r = (u + 0x7fffu + ((u >> 16) & 1u)) >> 16;   // RNE
    return (short)r;
}
__device__ __forceinline__ float bf2f(short s) {
    return __builtin_bit_cast(float, ((u32)(unsigned short)s) << 16);
}
__device__ __forceinline__ u32 cvtpk(float lo, float hi) {
    u32 r;
    asm("v_cvt_pk_bf16_f32 %0, %1, %2" : "=v"(r) : "v"(lo), "v"(hi));
    return r;
}
__device__ __forceinline__ void async_copy16(void* lds, const void* g) {
    __builtin_amdgcn_global_load_lds((const __attribute__((address_space(1))) u32*)g,
                                     (__attribute__((address_space(3))) u32*)lds, 16, 0, 0);
}

// ---------------------------------------------------------------------------
// prep_all: fused {cast_x | transpose_w | tables + maskP(log2-domain)}
// ---------------------------------------------------------------------------
__global__ __launch_bounds__(256)
void prep_all(const float* __restrict__ x, short* __restrict__ xb,
              const float* __restrict__ wq, const float* __restrict__ wk,
              const float* __restrict__ wv, const float* __restrict__ wo,
              short* __restrict__ Wtqkv, short* __restrict__ Wto,
              const float* __restrict__ relk, const float* __restrict__ relv,
              short* __restrict__ relkb, short* __restrict__ relvT,
              const float* __restrict__ mask, short* __restrict__ maskPb)
{
    __shared__ float sT[64][68];
    const int bid = blockIdx.x;
    const int tid = threadIdx.x;

    if (bid < 2048) {
        int i = (bid * 256 + tid) * 8;
        float4 a = *(const float4*)&x[i];
        float4 b = *(const float4*)&x[i + 4];
        s16x8 v = { f2bf(a.x), f2bf(a.y), f2bf(a.z), f2bf(a.w),
                    f2bf(b.x), f2bf(b.y), f2bf(b.z), f2bf(b.w) };
        *(s16x8*)&xb[i] = v;
    } else if (bid < 3072) {
        const int wid = bid - 2048;
        const int kt = wid & 15, nt = (wid >> 4) & 15, seg = wid >> 8;
        const float* src = seg == 0 ? wq : seg == 1 ? wk : seg == 2 ? wv : wo;
        const int k0 = kt * 64, n0 = nt * 64;
#pragma unroll
        for (int i = 0; i < 4; ++i) {
            int t2 = tid + i * 256;
            int r = t2 >> 4, c4 = t2 & 15;
            *(float4*)&sT[r][c4 * 4] = *(const float4*)&src[(size_t)(k0 + r) * 1024 + n0 + c4 * 4];
        }
        __syncthreads();
#pragma unroll
        for (int i = 0; i < 2; ++i) {
            int t2 = tid + i * 256;
            int rn = t2 >> 3, ch = t2 & 7;
            s16x8 v;
#pragma unroll
            for (int j = 0; j < 8; ++j) v[j] = f2bf(sT[ch * 8 + j][rn]);
            if (seg < 3)
                *(s16x8*)&Wtqkv[(size_t)(seg * 1024 + n0 + rn) * 1024 + k0 + ch * 8] = v;
            else
                *(s16x8*)&Wto[(size_t)(n0 + rn) * 1024 + k0 + ch * 8] = v;
        }
    } else {
        int gt = (bid - 3072) * 256 + tid;
        for (int i = gt; i < 144 * 64; i += 256 * 8) {
            int r = i >> 6, d = i & 63;
            relkb[i] = (r < 129) ? f2bf(relk[r * 64 + d]) : (short)0;
        }
        for (int i = gt; i < 64 * 128; i += 256 * 8) {
            int d = i >> 7, r = i & 127;
            relvT[i] = f2bf(relv[r * 64 + d]);
        }
        for (int i = gt; i < 4096; i += 256 * 8)
            maskPb[i] = f2bf(mask[i] * (-1e9f * LOG2E));
    }
}

// ---------------------------------------------------------------------------
// Fused QKV GEMM; Q segment scaled by log2(e) (exp2 softmax domain).
// ---------------------------------------------------------------------------
__global__ __launch_bounds__(256, 4)
void gemm_qkv(const short* __restrict__ Ab, const short* __restrict__ Wt,
              const float* __restrict__ bq, const float* __restrict__ bk,
              const float* __restrict__ bv,
              short* __restrict__ Qb, short* __restrict__ Kb, short* __restrict__ Vtb)
{
    __shared__ __align__(16) short As[128 * 64];
    __shared__ __align__(16) short Bs[128 * 64];
    const int tid = threadIdx.x;
    const int w = tid >> 6, lane = tid & 63;
    const int lo16 = lane & 15, hi = lane >> 4;
    const int pb = blockIdx.x;
    const int wg = (pb & 7) * 96 + (pb >> 3);
    const int n0g = (wg % 24) * 128;
    const int m0 = (wg / 24) * 128;
    const int wr = w >> 1, wc = w & 1;

    f32x4 acc[4][4] = {};

    for (int t = 0; t < 16; ++t) {
        const int k0 = t * 64;
        __syncthreads();
#pragma unroll
        for (int i = 0; i < 4; ++i) {
            int o = i * 4096 + tid * 16;
            int row = o >> 7;
            int cb = o & 127;
            int sc = cb ^ ((row & 7) << 4);
            async_copy16((char*)As + o, Ab + (size_t)(m0 + row) * 1024 + k0 + (sc >> 1));
            async_copy16((char*)Bs + o, Wt + (size_t)(n0g + row) * 1024 + k0 + (sc >> 1));
        }
        __syncthreads();
#pragma unroll
        for (int ks = 0; ks < 2; ++ks) {
            s16x8 aF[4], bF[4];
#pragma unroll
            for (int mi = 0; mi < 4; ++mi) {
                int row = wr * 64 + mi * 16 + lo16;
                int cb = ks * 64 + hi * 16;
                aF[mi] = *(const s16x8*)((const char*)As + row * 128 + (cb ^ ((row & 7) << 4)));
            }
#pragma unroll
            for (int ni = 0; ni < 4; ++ni) {
                int row = wc * 64 + ni * 16 + lo16;
                int cb = ks * 64 + hi * 16;
                bF[ni] = *(const s16x8*)((const char*)Bs + row * 128 + (cb ^ ((row & 7) << 4)));
            }
#pragma unroll
            for (int mi = 0; mi < 4; ++mi)
#pragma unroll
                for (int ni = 0; ni < 4; ++ni)
                    acc[mi][ni] = MFMA(aF[mi], bF[ni], acc[mi][ni]);
        }
    }

    const int seg = n0g >> 10;
    const int nn = n0g & 1023;
    const float* bias = seg == 0 ? bq : seg == 1 ? bk : bv;
    const float oscale = (seg == 0) ? LOG2E : 1.0f;   // Q in log2-exp domain
    float bv4[4];
#pragma unroll
    for (int ni = 0; ni < 4; ++ni) bv4[ni] = bias[nn + wc * 64 + ni * 16 + lo16];

    if (seg == 2) {
#pragma unroll
        for (int mi = 0; mi < 4; ++mi)
#pragma unroll
            for (int ni = 0; ni < 4; ++ni) {
                int nl = nn + wc * 64 + ni * 16 + lo16;
                int hh = nl >> 6, d = nl & 63;
                int mbase = m0 + wr * 64 + mi * 16 + hi * 4;
                int bb = mbase >> 10, l0 = mbase & 1023;
                int j0 = l0 & 31;
                int col = (l0 >> 5) * 32 + (((j0 >> 4) & 1) << 2) + (((j0 >> 2) & 3) << 3);
                s16x4 pk = { f2bf(acc[mi][ni][0] + bv4[ni]),
                             f2bf(acc[mi][ni][1] + bv4[ni]),
                             f2bf(acc[mi][ni][2] + bv4[ni]),
                             f2bf(acc[mi][ni][3] + bv4[ni]) };
                *(s16x4*)&Vtb[((size_t)(bb * 16 + hh) * 64 + d) * 1024 + col] = pk;
            }
    } else {
        short* out = seg == 0 ? Qb : Kb;
#pragma unroll
        for (int mi = 0; mi < 4; ++mi)
#pragma unroll
            for (int ni = 0; ni < 4; ++ni) {
                int nl = nn + wc * 64 + ni * 16 + lo16;
                int hh = nl >> 6, d = nl & 63;
#pragma unroll
                for (int r = 0; r < 4; ++r) {
                    int m = m0 + wr * 64 + mi * 16 + hi * 4 + r;
                    int bb = m >> 10, l = m & 1023;
                    out[(((size_t)bb * 16 + hh) * 1024 + l) * 64 + d] =
                        f2bf((acc[mi][ni][r] + bv4[ni]) * oscale);
                }
            }
    }
}

// ---------------------------------------------------------------------------
// Flash attention v14: cross-iteration QK pipelining. S(t+1) computed during
// iteration t (QK MFMA latency off the softmax critical path; MFMA pipe runs
// concurrent with softmax VALU). 3 LDS buffers (read {t, t+1}, write {t+2}).
// LDS = 12K(K) + 12K(V) + 16K(QB) = 40960B -> 4 blocks/CU.
// Sync: one __syncthreads per iteration (same proven protocol).
// ---------------------------------------------------------------------------
__global__ __launch_bounds__(256, 4)
void attn_mfma(const short* __restrict__ Qb, const short* __restrict__ Kb,
               const short* __restrict__ Vtb, const short* __restrict__ relkb,
               const short* __restrict__ relvTb, const float* __restrict__ relv_f32,
               const short* __restrict__ maskPb, short* __restrict__ CTXb)
{
    __shared__ __align__(16) short sK[3][32 * 64];     // 12288B
    __shared__ __align__(16) short sV[3][64 * 32];     // 12288B
    __shared__ __align__(16) short sQB[4][16][128];    // 16384B, Qrel->band in place, idx ^ qsw

    const int tid = threadIdx.x;
    const int w = tid >> 6, lane = tid & 63;
    const int lo16 = lane & 15, hi = lane >> 4;
    const int qsw = (lo16 & 7) << 4;         // bank swizzle
    const int vm = (lo16 >> 1) & 3;          // V chunk swizzle

    const int p = blockIdx.x;
    const int bid = (p & 7) * 128 + (p >> 3);
    const int bh = bid >> 4;
    const int qt = bid & 15;
    const int b = bh >> 4, h = bh & 15;
    const int q0 = qt * 64 + w * 16;
    const int q_abs = q0 + lo16;

    const short* Kbase = Kb + (size_t)bh * 65536;
    const short* Vtbase = Vtb + (size_t)bh * 65536;
    const short* mbase = maskPb + b * 1024;

    const int skr = tid >> 3, skc = tid & 7;             // K: row 0..31, chunk 0..7
    const int svd = tid >> 2, svc = tid & 3;             // V: row d 0..63, chunk 0..3
    const short* ksrc = Kbase + (size_t)skr * 64 + ((skc ^ (skr & 7)) << 3);
    const short* vsrc = Vtbase + (size_t)svd * 1024 + ((svc ^ ((svd >> 1) & 3)) << 3);

    // stage chunks 0 and 1
    async_copy16((char*)&sK[0][0] + tid * 16, ksrc);
    async_copy16((char*)&sV[0][0] + tid * 16, vsrc);
    async_copy16((char*)&sK[1][0] + tid * 16, ksrc + (size_t)32 * 64);
    async_copy16((char*)&sV[1][0] + tid * 16, vsrc + 32);

    const short* qptr = Qb + ((size_t)bh * 1024 + q_abs) * 64 + hi * 8;
    const s16x8 qB0 = *(const s16x8*)qptr;
    const s16x8 qB1 = *(const s16x8*)(qptr + 32);

    // Qrel init: rf 0..7 -> sQB[w][q][(0..127)^qsw]; rf=8 kept in regs
    f32x4 dq8 = {0.f, 0.f, 0.f, 0.f};
#pragma unroll
    for (int rf = 0; rf < 9; ++rf) {
        const short* rp = relkb + (size_t)(rf * 16 + lo16) * 64 + hi * 8;
        s16x8 rA0 = *(const s16x8*)rp;
        s16x8 rA1 = *(const s16x8*)(rp + 32);
        f32x4 dq = {0.f, 0.f, 0.f, 0.f};
        dq = MFMA(rA0, qB0, dq);
        dq = MFMA(rA1, qB1, dq);
        if (rf < 8) {
            s16x4 pk = { f2bf(dq[0]), f2bf(dq[1]), f2bf(dq[2]), f2bf(dq[3]) };
            *(s16x4*)&sQB[w][lo16][(rf * 16 + hi * 4) ^ qsw] = pk;
        } else {
            dq8 = dq;
        }
    }
    const float qrel_lo = bf2f(sQB[w][lo16][0 ^ qsw]);
    const float qrel_hi = __shfl(bf2f(f2bf(dq8[0])), lo16);

    __syncthreads();   // drains chunk-0/1 staging; fences sQB init

    f32x4 ctx[4] = {};
    float lsum = 0.f, lov = 0.f, hiv = 0.f;
    const f32x4 z = {0.f, 0.f, 0.f, 0.f};
    const int km = lo16 & 7;

    // rotating buffer pointers: cur (V of chunk t), nxt (K of chunk t+1),
    // stg (staging target, chunk t+2)
    const short* sKc = sK[0]; const short* sKn = sK[1]; const short* sKs = sK[2];
    const short* sVc = sV[0]; const short* sVn = sV[1]; const short* sVs = sV[2];

    // prologue: QK(0) from buf 0
    f32x4 cS0, cS1;
    {
        s16x8 kr0 = *(const s16x8*)(sKc + lo16 * 64 + ((hi ^ km) << 3));
        s16x8 kr1 = *(const s16x8*)(sKc + lo16 * 64 + (((hi + 4) ^ km) << 3));
        s16x8 kr2 = *(const s16x8*)(sKc + (lo16 + 16) * 64 + ((hi ^ km) << 3));
        s16x8 kr3 = *(const s16x8*)(sKc + (lo16 + 16) * 64 + (((hi + 4) ^ km) << 3));
        cS0 = MFMA(kr0, qB0, z);
        cS1 = MFMA(kr2, qB0, z);
        cS0 = MFMA(kr1, qB1, cS0);
        cS1 = MFMA(kr3, qB1, cS1);
    }

    for (int t = 0; t < 32; ++t) {
        const int kf = t * 32;
        // ---- stage chunk t+2 into stg buffer ----
        const int kfn = ((t + 2) & 31) * 32;
        async_copy16((char*)sKs + tid * 16, ksrc + (size_t)kfn * 64);
        async_copy16((char*)sVs + tid * 16, vsrc + kfn);
        // ---- V(t) + mask(t) ----
        s16x8 vr0 = *(const s16x8*)(sVc + lo16 * 32 + ((hi ^ vm) << 3));
        s16x8 vr1 = *(const s16x8*)(sVc + (16 + lo16) * 32 + ((hi ^ vm) << 3));
        s16x8 vr2 = *(const s16x8*)(sVc + (32 + lo16) * 32 + ((hi ^ vm) << 3));
        s16x8 vr3 = *(const s16x8*)(sVc + (48 + lo16) * 32 + ((hi ^ vm) << 3));
        s16x4 m0 = *(const s16x4*)&mbase[kf + hi * 4];
        s16x4 m1 = *(const s16x4*)&mbase[kf + 16 + hi * 4];
        // ---- K(t+1) + QK(t+1) (concurrent with softmax(t) below) ----
        s16x8 kr0 = *(const s16x8*)(sKn + lo16 * 64 + ((hi ^ km) << 3));
        s16x8 kr1 = *(const s16x8*)(sKn + lo16 * 64 + (((hi + 4) ^ km) << 3));
        s16x8 kr2 = *(const s16x8*)(sKn + (lo16 + 16) * 64 + ((hi ^ km) << 3));
        s16x8 kr3 = *(const s16x8*)(sKn + (lo16 + 16) * 64 + (((hi + 4) ^ km) << 3));
        __builtin_amdgcn_s_setprio(1);
        f32x4 nS0 = MFMA(kr0, qB0, z);
        f32x4 nS1 = MFMA(kr2, qB0, z);
        nS0 = MFMA(kr1, qB1, nS0);
        nS1 = MFMA(kr3, qB1, nS1);
        __builtin_amdgcn_s_setprio(0);

        // ---- softmax(t) on cS (ready since last iteration; no MFMA wait) ----
        float pr[8];
        if (kf + 95 <= q0 || kf >= q0 + 79) {
            const float qc = (kf < q0) ? qrel_lo : qrel_hi;
            float bs = 0.f;
#pragma unroll
            for (int r = 0; r < 4; ++r) {
                pr[r]     = fexp2(cS0[r] + qc + bf2f(m0[r]));
                pr[4 + r] = fexp2(cS1[r] + qc + bf2f(m1[r]));
            }
#pragma unroll
            for (int r = 0; r < 8; ++r) bs += pr[r];
            lsum += bs;
            if (kf < q0) lov += bs; else hiv += bs;
        } else {
#pragma unroll
            for (int f = 0; f < 2; ++f)
#pragma unroll
                for (int r = 0; r < 4; ++r) {
                    int k_abs = kf + f * 16 + hi * 4 + r;
                    int dd = k_abs - q_abs;
                    dd = dd < -64 ? -64 : (dd > 64 ? 64 : dd);
                    int rel = dd + 64;
                    int relc = rel > 127 ? 127 : rel;
                    float qv = bf2f(sQB[w][lo16][relc ^ qsw]);   // gather Qrel
                    if (rel == 128) qv = qrel_hi;
                    float sv = f ? cS1[r] : cS0[r];
                    float mv = bf2f(f ? m1[r] : m0[r]);
                    float pex = fexp2(sv + qv + mv);
                    pr[f * 4 + r] = pex;
                    lsum += pex;
                    if (rel >= 1 && rel <= 127) sQB[w][lo16][rel ^ qsw] = f2bf(pex);  // scatter band
                    else if (rel == 0) lov += pex;
                    else hiv += pex;
                }
        }
        u32x2 w0 = { cvtpk(pr[0], pr[1]), cvtpk(pr[2], pr[3]) };
        u32x2 w1 = { cvtpk(pr[4], pr[5]), cvtpk(pr[6], pr[7]) };
        s16x4 pf0 = __builtin_bit_cast(s16x4, w0);
        s16x4 pf1 = __builtin_bit_cast(s16x4, w1);

        // ---- PV(t) (8 MFMAs) ----
        s16x4 a0 = __builtin_shufflevector(vr0, vr0, 0, 1, 2, 3);
        s16x4 b0 = __builtin_shufflevector(vr0, vr0, 4, 5, 6, 7);
        s16x4 a1 = __builtin_shufflevector(vr1, vr1, 0, 1, 2, 3);
        s16x4 b1 = __builtin_shufflevector(vr1, vr1, 4, 5, 6, 7);
        s16x4 a2 = __builtin_shufflevector(vr2, vr2, 0, 1, 2, 3);
        s16x4 b2 = __builtin_shufflevector(vr2, vr2, 4, 5, 6, 7);
        s16x4 a3 = __builtin_shufflevector(vr3, vr3, 0, 1, 2, 3);
        s16x4 b3 = __builtin_shufflevector(vr3, vr3, 4, 5, 6, 7);
        __builtin_amdgcn_s_setprio(1);
        ctx[0] = MFMA16(a0, pf0, ctx[0]);
        ctx[1] = MFMA16(a1, pf0, ctx[1]);
        ctx[2] = MFMA16(a2, pf0, ctx[2]);
        ctx[3] = MFMA16(a3, pf0, ctx[3]);
        ctx[0] = MFMA16(b0, pf1, ctx[0]);
        ctx[1] = MFMA16(b1, pf1, ctx[1]);
        ctx[2] = MFMA16(b2, pf1, ctx[2]);
        ctx[3] = MFMA16(b3, pf1, ctx[3]);
        __builtin_amdgcn_s_setprio(0);

        cS0 = nS0; cS1 = nS1;
        // rotate buffers: cur <- nxt <- stg <- cur
        const short* tk = sKc; sKc = sKn; sKn = sKs; sKs = tk;
        const short* tv = sVc; sVc = sVn; sVn = sVs; sVs = tv;

        __syncthreads();   // drains this iter's staging + all waves' reads
    }

    // ---- finalize band array: zero slot 0 and unvisited edge slots ----
    if (hi == 0) {
        sQB[w][lo16][0 ^ qsw] = 0;
        if (qt == 0) {
            for (int rel = 1; rel <= 63 - q_abs; ++rel)
                sQB[w][lo16][rel ^ qsw] = 0;
        } else if (qt == 15) {
            for (int rel = 1088 - q_abs; rel <= 127; ++rel)
                sQB[w][lo16][rel ^ qsw] = 0;
        }
    }
    __syncthreads();

    // band rel_v contribution: ctx^T += relvT-frag x band-frag (unnormalized)
#pragma unroll
    for (int ks = 0; ks < 4; ++ks) {
        s16x8 bB = *(const s16x8*)&sQB[w][lo16][(ks * 32 + hi * 8) ^ qsw];
#pragma unroll
        for (int df = 0; df < 4; ++df) {
            s16x8 rA = *(const s16x8*)(relvTb + (size_t)(df * 16 + lo16) * 128 + ks * 32 + hi * 8);
            ctx[df] = MFMA(rA, bB, ctx[df]);
        }
    }

    // reduce per-q stats across the 4 hi-groups
    lsum += __shfl_xor(lsum, 16); lsum += __shfl_xor(lsum, 32);
    lov  += __shfl_xor(lov, 16);  lov  += __shfl_xor(lov, 32);
    hiv  += __shfl_xor(hiv, 16);  hiv  += __shfl_xor(hiv, 32);
    const float inv = 1.0f / lsum;

    // tails (clipped buckets 0 / 128) + normalize + store bf16 ctx
#pragma unroll
    for (int df = 0; df < 4; ++df) {
        s16x4 pk;
#pragma unroll
        for (int r = 0; r < 4; ++r) {
            int d = df * 16 + hi * 4 + r;
            float t = ctx[df][r] + lov * relv_f32[d] + hiv * relv_f32[128 * 64 + d];
            pk[r] = f2bf(t * inv);
        }
        *(s16x4*)(CTXb + ((size_t)(b * 1024) + q_abs) * 1024 + h * 64 + df * 16 + hi * 4) = pk;
    }
}

// ---------------------------------------------------------------------------
// Output GEMM (unchanged): 128x64 tile, 512 blocks, XCD-swizzled.
// ---------------------------------------------------------------------------
__global__ __launch_bounds__(256, 4)
void gemm_out(const short* __restrict__ Ab, const short* __restrict__ Wto,
              const float* __restrict__ bo, float* __restrict__ out)
{
    __shared__ __align__(16) short As[128 * 64];
    __shared__ __align__(16) short Bs[64 * 64];
    const int tid = threadIdx.x;
    const int w = tid >> 6, lane = tid & 63;
    const int lo16 = lane & 15, hi = lane >> 4;
    const int pb = blockIdx.x;
    const int wg = (pb & 7) * 64 + (pb >> 3);
    const int n0 = (wg & 15) * 64;
    const int m0 = (wg >> 4) * 128;
    const int wr = w;

    f32x4 acc[2][4] = {};

    for (int t = 0; t < 16; ++t) {
        const int k0 = t * 64;
        __syncthreads();
#pragma unroll
        for (int i = 0; i < 4; ++i) {
            int o = i * 4096 + tid * 16;
            int row = o >> 7;
            int cb = o & 127;
            int sc = cb ^ ((row & 7) << 4);
            async_copy16((char*)As + o, Ab + (size_t)(m0 + row) * 1024 + k0 + (sc >> 1));
        }
#pragma unroll
        for (int i = 0; i < 2; ++i) {
            int o = i * 4096 + tid * 16;
            int row = o >> 7;
            int cb = o & 127;
            int sc = cb ^ ((row & 7) << 4);
            async_copy16((char*)Bs + o, Wto + (size_t)(n0 + row) * 1024 + k0 + (sc >> 1));
        }
        __syncthreads();
#pragma unroll
        for (int ks = 0; ks < 2; ++ks) {
            s16x8 aF[2], bF[4];
#pragma unroll
            for (int mi = 0; mi < 2; ++mi) {
                int row = wr * 32 + mi * 16 + lo16;
                int cb = ks * 64 + hi * 16;
                aF[mi] = *(const s16x8*)((const char*)As + row * 128 + (cb ^ ((row & 7) << 4)));
            }
#pragma unroll
            for (int ni = 0; ni < 4; ++ni) {
                int row = ni * 16 + lo16;
                int cb = ks * 64 + hi * 16;
                bF[ni] = *(const s16x8*)((const char*)Bs + row * 128 + (cb ^ ((row & 7) << 4)));
            }
#pragma unroll
            for (int mi = 0; mi < 2; ++mi)
#pragma unroll
                for (int ni = 0; ni < 4; ++ni)
                    acc[mi][ni] = MFMA(aF[mi], bF[ni], acc[mi][ni]);
        }
    }

    float bv4[4];
#pragma unroll
    for (int ni = 0; ni < 4; ++ni) bv4[ni] = bo[n0 + ni * 16 + lo16];
#pragma unroll
    for (int mi = 0; mi < 2; ++mi)
#pragma unroll
        for (int ni = 0; ni < 4; ++ni)
#pragma unroll
            for (int r = 0; r < 4; ++r) {
                int m = m0 + wr * 32 + mi * 16 + hi * 4 + r;
                out[(size_t)m * 1024 + n0 + ni * 16 + lo16] = acc[mi][ni][r] + bv4[ni];
            }
}

// ---------------------------------------------------------------------------
extern "C" void kernel_launch(void* const* d_in, const int* in_sizes, int n_in,
                              void* d_out, int out_size, void* d_ws, size_t ws_size,
                              hipStream_t stream)
{
    (void)in_sizes; (void)n_in; (void)out_size; (void)ws_size;
    const float* x    = (const float*)d_in[0];
    const float* mask = (const float*)d_in[1];
    const float* wq   = (const float*)d_in[2];
    const float* bq   = (const float*)d_in[3];
    const float* wk   = (const float*)d_in[4];
    const float* bk   = (const float*)d_in[5];
    const float* wv   = (const float*)d_in[6];
    const float* bv   = (const float*)d_in[7];
    const float* wo   = (const float*)d_in[8];
    const float* bo   = (const float*)d_in[9];
    const float* relk = (const float*)d_in[10];
    const float* relv = (const float*)d_in[11];
    float* out = (float*)d_out;

    char* p = (char*)d_ws;
    short* xb     = (short*)p; p += (size_t)4096 * 1024 * 2;     // 8 MB
    short* Wtqkv  = (short*)p; p += (size_t)3072 * 1024 * 2;     // 6 MB
    short* Wto    = (short*)p; p += (size_t)1024 * 1024 * 2;     // 2 MB
    short* Qb     = (short*)p; p += (size_t)4096 * 1024 * 2;     // 8 MB
    short* Kb     = (short*)p; p += (size_t)4096 * 1024 * 2;     // 8 MB
    short* Vtb    = (short*)p; p += (size_t)4096 * 1024 * 2;     // 8 MB
    short* CTXb   = (short*)p; p += (size_t)4096 * 1024 * 2;     // 8 MB
    short* relkb  = (short*)p; p += (size_t)144 * 64 * 2;
    short* relvT  = (short*)p; p += (size_t)64 * 128 * 2;
    short* maskPb = (short*)p; p += (size_t)4096 * 2;

    prep_all  <<<3080, 256, 0, stream>>>(x, xb, wq, wk, wv, wo, Wtqkv, Wto,
                                         relk, relv, relkb, relvT, mask, maskPb);
    gemm_qkv  <<<768, 256, 0, stream>>>(xb, Wtqkv, bq, bk, bv, Qb, Kb, Vtb);
    attn_mfma <<<1024, 256, 0, stream>>>(Qb, Kb, Vtb, relkb, relvT, relv, maskPb, CTXb);
    gemm_out  <<<512, 256, 0, stream>>>(CTXb, Wto, bo, out);
}